// Round 1
// baseline (465.202 us; speedup 1.0000x reference)
//
#include <hip/hip_runtime.h>
#include <hip/hip_bf16.h>

#define S_LEN 2048
#define DMODEL 1024
#define NHEAD 16
#define DHEAD 64
#define BATCH 4
#define MTOT (BATCH * S_LEN)   // 8192 rows

typedef __attribute__((ext_vector_type(8))) short short8;
typedef __attribute__((ext_vector_type(8))) unsigned short ushort8;
typedef __attribute__((ext_vector_type(4))) float f32x4;

__device__ __forceinline__ unsigned short f2bf(float x) {
    unsigned int u = __float_as_uint(x);
    u += 0x7FFFu + ((u >> 16) & 1u);   // RNE
    return (unsigned short)(u >> 16);
}

// ---------------- fp32 -> bf16 elementwise convert (8 elems/thread) ----------------
__global__ __launch_bounds__(256) void k_conv_bf16(const float* __restrict__ src,
                                                   unsigned short* __restrict__ dst, int n8) {
    int i = blockIdx.x * 256 + threadIdx.x;
    if (i >= n8) return;
    const float4* s4 = (const float4*)src;
    float4 a = s4[(size_t)i * 2];
    float4 b = s4[(size_t)i * 2 + 1];
    ushort8 v;
    v[0] = f2bf(a.x); v[1] = f2bf(a.y); v[2] = f2bf(a.z); v[3] = f2bf(a.w);
    v[4] = f2bf(b.x); v[5] = f2bf(b.y); v[6] = f2bf(b.z); v[7] = f2bf(b.w);
    *(ushort8*)(dst + (size_t)i * 8) = v;
}

// ---------------- weight transpose-convert: W[k][n] f32 -> Wt[n][k] bf16 ----------------
__global__ __launch_bounds__(256) void k_transpose_w(const float* __restrict__ W0, const float* __restrict__ W1,
                                                     const float* __restrict__ W2, const float* __restrict__ W3,
                                                     unsigned short* __restrict__ T0, unsigned short* __restrict__ T1,
                                                     unsigned short* __restrict__ T2, unsigned short* __restrict__ T3) {
    const float* src; unsigned short* dst;
    switch (blockIdx.z) {
        case 0: src = W0; dst = T0; break;
        case 1: src = W1; dst = T1; break;
        case 2: src = W2; dst = T2; break;
        default: src = W3; dst = T3; break;
    }
    __shared__ float t[32][33];
    int tx = threadIdx.x & 31, ty = threadIdx.x >> 5;  // 32 x 8
    int n0 = blockIdx.x * 32, k0 = blockIdx.y * 32;
#pragma unroll
    for (int i = 0; i < 32; i += 8)
        t[ty + i][tx] = src[(size_t)(k0 + ty + i) * DMODEL + n0 + tx];
    __syncthreads();
#pragma unroll
    for (int i = 0; i < 32; i += 8)
        dst[(size_t)(n0 + ty + i) * DMODEL + k0 + tx] = f2bf(t[tx][ty + i]);
}

// ---------------- NT GEMM: C[M][N] = A[M][K] * Bt[N][K]^T + bias, scaled by alpha ----------------
// 128x128 tile, BK=32, 4 waves each computing 64x64 (4x4 fragments of 16x16x32 MFMA).
template <int OUT_FP32>
__global__ __launch_bounds__(256) void k_gemm_nt(const unsigned short* __restrict__ A,
                                                 const unsigned short* __restrict__ Bt,
                                                 const float* __restrict__ bias,
                                                 void* __restrict__ Cout,
                                                 int M, int N, int K, float alpha) {
    __shared__ unsigned short Al[128 * 32];
    __shared__ unsigned short Bl[128 * 32];
    int tid = threadIdx.x;
    int wid = tid >> 6;
    int lane = tid & 63;
    int lr = lane & 15, lg = lane >> 4;
    int bm = blockIdx.y * 128, bn = blockIdx.x * 128;
    int wm = (wid >> 1) * 64, wn = (wid & 1) * 64;

    f32x4 acc[4][4];
#pragma unroll
    for (int mt = 0; mt < 4; ++mt)
#pragma unroll
        for (int nt = 0; nt < 4; ++nt) acc[mt][nt] = (f32x4)0.0f;

    for (int k0 = 0; k0 < K; k0 += 32) {
        // stage A,B tiles (each 128x32 bf16 = 8KB) via global_load_lds width 16
#pragma unroll
        for (int i = 0; i < 2; ++i) {
            int c = (wid * 2 + i) * 64 + lane;     // 16B chunk index 0..511
            int row = c >> 2, cc = c & 3;
            const unsigned short* ga = A + (size_t)(bm + row) * K + k0 + cc * 8;
            const unsigned short* gb = Bt + (size_t)(bn + row) * K + k0 + cc * 8;
            __builtin_amdgcn_global_load_lds((const __attribute__((address_space(1))) unsigned int*)ga,
                                             (__attribute__((address_space(3))) unsigned int*)(Al + (wid * 2 + i) * 512),
                                             16, 0, 0);
            __builtin_amdgcn_global_load_lds((const __attribute__((address_space(1))) unsigned int*)gb,
                                             (__attribute__((address_space(3))) unsigned int*)(Bl + (wid * 2 + i) * 512),
                                             16, 0, 0);
        }
        __syncthreads();

        short8 af[4], bf[4];
#pragma unroll
        for (int mt = 0; mt < 4; ++mt)
            af[mt] = *(const short8*)(Al + (wm + mt * 16 + lr) * 32 + lg * 8);
#pragma unroll
        for (int nt = 0; nt < 4; ++nt)
            bf[nt] = *(const short8*)(Bl + (wn + nt * 16 + lr) * 32 + lg * 8);
#pragma unroll
        for (int mt = 0; mt < 4; ++mt)
#pragma unroll
            for (int nt = 0; nt < 4; ++nt)
                acc[mt][nt] = __builtin_amdgcn_mfma_f32_16x16x32_bf16(af[mt], bf[nt], acc[mt][nt], 0, 0, 0);
        __syncthreads();
    }

    // epilogue: C[row][col], row=(lg*4+r) within fragment, col=lr
#pragma unroll
    for (int nt = 0; nt < 4; ++nt) {
        int col = bn + wn + nt * 16 + lr;
        float bv = bias[col];
#pragma unroll
        for (int mt = 0; mt < 4; ++mt) {
#pragma unroll
            for (int r = 0; r < 4; ++r) {
                int row = bm + wm + mt * 16 + lg * 4 + r;
                float v = (acc[mt][nt][r] + bv) * alpha;
                if (OUT_FP32)
                    ((float*)Cout)[(size_t)row * N + col] = v;
                else
                    ((unsigned short*)Cout)[(size_t)row * N + col] = f2bf(v);
            }
        }
    }
}

// ---------------- causal flash attention, one wave per 64-row Q block ----------------
// Computes S^T = mfma(K, Q) so softmax rows are lane-local columns; PV uses a custom
// k-slot bijection so P^T feeds the B operand directly from registers.
__global__ __launch_bounds__(64, 2) void k_attn(const unsigned short* __restrict__ Qp,
                                                const unsigned short* __restrict__ Kp,
                                                const unsigned short* __restrict__ Vp,
                                                unsigned short* __restrict__ Ctx) {
    int lane = threadIdx.x & 63;
    int lr = lane & 15, lg = lane >> 4;
    int qb = blockIdx.x;           // 0..31  (64-row q block)
    int bh = blockIdx.y;           // 0..63
    int b = bh >> 4, h = bh & 15;
    size_t baserow = (size_t)b * S_LEN;
    int hcol = h * DHEAD;

    // Q fragments (pre-scaled by 1/8 at projection time)
    short8 qf[4][2];
#pragma unroll
    for (int qt = 0; qt < 4; ++qt)
#pragma unroll
        for (int ks = 0; ks < 2; ++ks)
            qf[qt][ks] = *(const short8*)(Qp + (baserow + qb * 64 + qt * 16 + lr) * DMODEL + hcol + ks * 32 + lg * 8);

    f32x4 ctx[4][4];   // [dt][qt] : ctx^T fragments
#pragma unroll
    for (int dt = 0; dt < 4; ++dt)
#pragma unroll
        for (int qt = 0; qt < 4; ++qt) ctx[dt][qt] = (f32x4)0.0f;

    float mrun[4], lrun[4];
#pragma unroll
    for (int qt = 0; qt < 4; ++qt) { mrun[qt] = -1e30f; lrun[qt] = 0.0f; }

    for (int kb = 0; kb <= qb; ++kb) {
        // ---- S^T = K * Q^T  (A = K rows, B = Q rows) ----
        f32x4 s[4][4];   // [kt][qt]
#pragma unroll
        for (int kt = 0; kt < 4; ++kt)
#pragma unroll
            for (int qt = 0; qt < 4; ++qt) s[kt][qt] = (f32x4)0.0f;

#pragma unroll
        for (int kt = 0; kt < 4; ++kt) {
            short8 kf[2];
#pragma unroll
            for (int ks = 0; ks < 2; ++ks)
                kf[ks] = *(const short8*)(Kp + (baserow + kb * 64 + kt * 16 + lr) * DMODEL + hcol + ks * 32 + lg * 8);
#pragma unroll
            for (int qt = 0; qt < 4; ++qt)
#pragma unroll
                for (int ks = 0; ks < 2; ++ks)
                    s[kt][qt] = __builtin_amdgcn_mfma_f32_16x16x32_bf16(kf[ks], qf[qt][ks], s[kt][qt], 0, 0, 0);
        }

        if (kb == qb) {   // causal mask inside diagonal block: kk_local > q_local -> -inf
#pragma unroll
            for (int kt = 0; kt < 4; ++kt)
#pragma unroll
                for (int qt = 0; qt < 4; ++qt)
#pragma unroll
                    for (int r = 0; r < 4; ++r)
                        if (kt * 16 + lg * 4 + r > qt * 16 + lr) s[kt][qt][r] = -1e30f;
        }

        // ---- online softmax per q column; build P^T bf16 fragments ----
        short8 pf[4][2];
#pragma unroll
        for (int qt = 0; qt < 4; ++qt) {
            float mx = -1e30f;
#pragma unroll
            for (int kt = 0; kt < 4; ++kt)
#pragma unroll
                for (int r = 0; r < 4; ++r) mx = fmaxf(mx, s[kt][qt][r]);
            mx = fmaxf(mx, __shfl_xor(mx, 16));
            mx = fmaxf(mx, __shfl_xor(mx, 32));
            float mnew = fmaxf(mrun[qt], mx);
            float scale = __expf(mrun[qt] - mnew);
            mrun[qt] = mnew;
            float rs = 0.0f;
#pragma unroll
            for (int kt = 0; kt < 4; ++kt)
#pragma unroll
                for (int r = 0; r < 4; ++r) {
                    float p = __expf(s[kt][qt][r] - mnew);
                    s[kt][qt][r] = p;
                    rs += p;
                }
            rs += __shfl_xor(rs, 16);
            rs += __shfl_xor(rs, 32);
            lrun[qt] = lrun[qt] * scale + rs;
#pragma unroll
            for (int dt = 0; dt < 4; ++dt)
#pragma unroll
                for (int r = 0; r < 4; ++r) ctx[dt][qt][r] *= scale;
            // pack: pf[qt][ks][j] = P^T[kk = 32ks+16(j>>2)+4lg+(j&3)][q], matching V frag slots
#pragma unroll
            for (int ks = 0; ks < 2; ++ks)
#pragma unroll
                for (int j = 0; j < 8; ++j)
                    pf[qt][ks][j] = (short)f2bf(s[2 * ks + (j >> 2)][qt][j & 3]);
        }

        // ---- ctx^T += V^T * P^T ----
        const unsigned short* vbase = Vp + (baserow + kb * 64) * DMODEL + hcol + lr;
#pragma unroll
        for (int dt = 0; dt < 4; ++dt) {
#pragma unroll
            for (int ks = 0; ks < 2; ++ks) {
                short8 vf;
#pragma unroll
                for (int j = 0; j < 8; ++j) {
                    int kk = 32 * ks + 16 * (j >> 2) + 4 * lg + (j & 3);
                    vf[j] = (short)vbase[(size_t)kk * DMODEL + dt * 16];
                }
#pragma unroll
                for (int qt = 0; qt < 4; ++qt)
                    ctx[dt][qt] = __builtin_amdgcn_mfma_f32_16x16x32_bf16(vf, pf[qt][ks], ctx[dt][qt], 0, 0, 0);
            }
        }
    }

    // ---- normalize and store ctx (bf16), ctx[q][d] with d = dt*16 + lg*4 + r ----
#pragma unroll
    for (int qt = 0; qt < 4; ++qt) {
        float inv = 1.0f / lrun[qt];
#pragma unroll
        for (int dt = 0; dt < 4; ++dt) {
            unsigned int lo = (unsigned int)f2bf(ctx[dt][qt][0] * inv) | ((unsigned int)f2bf(ctx[dt][qt][1] * inv) << 16);
            unsigned int hi = (unsigned int)f2bf(ctx[dt][qt][2] * inv) | ((unsigned int)f2bf(ctx[dt][qt][3] * inv) << 16);
            uint2 vv; vv.x = lo; vv.y = hi;
            *(uint2*)(Ctx + (baserow + qb * 64 + qt * 16 + lr) * DMODEL + hcol + dt * 16 + lg * 4) = vv;
        }
    }
}

// ---------------- host launch ----------------
extern "C" void kernel_launch(void* const* d_in, const int* in_sizes, int n_in,
                              void* d_out, int out_size, void* d_ws, size_t ws_size,
                              hipStream_t stream) {
    const float* q_in = (const float*)d_in[0];
    const float* k_in = (const float*)d_in[1];
    const float* v_in = (const float*)d_in[2];
    // d_in[3] = mask (known causal triu; handled analytically)
    const float* Wq = (const float*)d_in[4];
    const float* bq = (const float*)d_in[5];
    const float* Wk = (const float*)d_in[6];
    const float* bk = (const float*)d_in[7];
    const float* Wv = (const float*)d_in[8];
    const float* bv = (const float*)d_in[9];
    const float* Wo = (const float*)d_in[10];
    const float* bo = (const float*)d_in[11];

    char* ws = (char*)d_ws;
    const size_t SZ_ACT = (size_t)MTOT * DMODEL * 2;   // 16,777,216 B
    const size_t SZ_W = (size_t)DMODEL * DMODEL * 2;   //  2,097,152 B
    unsigned short* Xq = (unsigned short*)(ws);
    unsigned short* Xk = (unsigned short*)(ws + SZ_ACT);
    unsigned short* Xv = (unsigned short*)(ws + 2 * SZ_ACT);
    unsigned short* Tq = (unsigned short*)(ws + 3 * SZ_ACT);
    unsigned short* Tk = (unsigned short*)(ws + 3 * SZ_ACT + SZ_W);
    unsigned short* Tv = (unsigned short*)(ws + 3 * SZ_ACT + 2 * SZ_W);
    unsigned short* To = (unsigned short*)(ws + 3 * SZ_ACT + 3 * SZ_W);
    unsigned short* Qp = (unsigned short*)(ws + 3 * SZ_ACT + 4 * SZ_W);
    unsigned short* Kp = (unsigned short*)(ws + 4 * SZ_ACT + 4 * SZ_W);
    unsigned short* Vp = (unsigned short*)(ws + 5 * SZ_ACT + 4 * SZ_W);
    unsigned short* Cx = (unsigned short*)(ws + 6 * SZ_ACT + 4 * SZ_W);

    int n8 = MTOT * DMODEL / 8;   // 1,048,576
    k_conv_bf16<<<(n8 + 255) / 256, 256, 0, stream>>>(q_in, Xq, n8);
    k_conv_bf16<<<(n8 + 255) / 256, 256, 0, stream>>>(k_in, Xk, n8);
    k_conv_bf16<<<(n8 + 255) / 256, 256, 0, stream>>>(v_in, Xv, n8);
    k_transpose_w<<<dim3(32, 32, 4), 256, 0, stream>>>(Wq, Wk, Wv, Wo, Tq, Tk, Tv, To);

    dim3 gg(DMODEL / 128, MTOT / 128);
    // fold the 1/sqrt(DH)=0.125 score scale into the Q projection (exact in bf16)
    k_gemm_nt<0><<<gg, 256, 0, stream>>>(Xq, Tq, bq, Qp, MTOT, DMODEL, DMODEL, 0.125f);
    k_gemm_nt<0><<<gg, 256, 0, stream>>>(Xk, Tk, bk, Kp, MTOT, DMODEL, DMODEL, 1.0f);
    k_gemm_nt<0><<<gg, 256, 0, stream>>>(Xv, Tv, bv, Vp, MTOT, DMODEL, DMODEL, 1.0f);

    k_attn<<<dim3(S_LEN / 64, BATCH * NHEAD), 64, 0, stream>>>(Qp, Kp, Vp, Cx);

    k_gemm_nt<1><<<gg, 256, 0, stream>>>(Cx, To, bo, d_out, MTOT, DMODEL, DMODEL, 1.0f);
}